// Round 2
// baseline (392.416 us; speedup 1.0000x reference)
//
#include <hip/hip_runtime.h>
#include <hip/hip_bf16.h>

// B=8, N=2048, DIN=256, DOUT=256
// Ne = H@W ; M1 = G@Ne ; M2 = G^T@Ne
// out[:,0:256]   = relu(0.5*(M1+M2))
// out[:,256:512] = relu(G^T @ (M1 * inv_rs))
// out[:,512:768] = relu(G   @ (M2 * inv_cs))

constexpr int NN = 2048;
constexpr long GSTR = (long)NN * NN;

using frag8   = __attribute__((ext_vector_type(8))) short;   // 8 bf16
using floatx4 = __attribute__((ext_vector_type(4))) float;
using ush8    = __attribute__((ext_vector_type(8))) unsigned short;

__device__ inline unsigned short f2bf(float x) {
    unsigned u = __float_as_uint(x);
    u += 0x7FFF + ((u >> 16) & 1);   // RNE
    return (unsigned short)(u >> 16);
}
__device__ inline float bf2f(unsigned short h) {
    return __uint_as_float((unsigned)h << 16);
}
__device__ inline ushort2 pk2(float a, float b) {
    union { __hip_bfloat162 h; ushort2 u; } cv;
    cv.h = __float22bfloat162_rn(float2{a, b});
    return cv.u;
}
__device__ inline void gload_lds16(const void* g, void* l) {
    __builtin_amdgcn_global_load_lds(
        (const __attribute__((address_space(1))) void*)g,
        (__attribute__((address_space(3))) void*)l, 16, 0, 0);
}

enum { EPI_NE = 0, EPI_M1 = 1, EPI_P2 = 2, EPI_O3 = 3 };
enum { A_F32ROW = 0, A_DMA = 1 };

// C[i,j] = sum_k Alog[i,k] * Bt[j,k]; Bt bf16 [n][K] staged via global_load_lds.
// LDS (As/Bs): row stride 64 shorts; 16B chunk c of row r at slot c^(r&7)
//   -> fragment ds_read_b128 2-way (free), staging fully coalesced (R6: 0 conflicts).
// Tile TM x 64, BK=64, 4 waves in 2x2 (wave = TM/2 rows x 32 cols).
// 1D grid, XCD-aware decode: xcd = bx&7 owns i-tiles {xcd, xcd+8, ...}; within an
// XCD the NJ j-tiles sharing an A-tile are temporally adjacent -> A-tile hits L2.
template <int EPI, int AMODE, int TM, int NJ>
__global__ __launch_bounds__(256) void mgemm(
    const void* __restrict__ Aptr,
    const unsigned short* __restrict__ B0,
    const unsigned short* __restrict__ B1,     // P2: M1sT (j0>=256 B-source + out1 reconstruct)
    const float* __restrict__ rsraw,           // P2: raw row sums (un-scale M1sT)
    unsigned short* __restrict__ CsT,          // transposed bf16 out [256][2048]
    float* __restrict__ outp,                  // fp32 out base (stride 768)
    const float* __restrict__ scale,           // M1: inv_rs ; P2: inv_cs
    int K, int lda, long strideA, long sB)
{
    constexpr int MF = TM / 32;                // m-frags per wave
    __shared__ __align__(16) unsigned short As[TM * 64];
    __shared__ __align__(16) unsigned short Bs[64 * 64];

    const int t  = threadIdx.x;
    const int bx = blockIdx.x;
    const int xcd = bx & 7;
    const int kk  = bx >> 3;
    constexpr int PER = NJ * 8;                // (j,b) combos per i-tile-group
    const int itile = xcd + 8 * (kk / PER);    // PER is pow2 -> shift
    const int rem   = kk & (PER - 1);
    const int bb    = rem / NJ;                // NJ pow2 -> shift
    const int jt    = rem & (NJ - 1);
    const int i0b = itile * TM;                // batch-local row tile
    const int j0  = jt * 64;

    const unsigned short* Btb =
        ((EPI == EPI_P2 && j0 >= 256) ? B1 + (long)(j0 - 256) * K
                                      : B0 + (long)j0 * K) + (long)bb * sB;

    const int w = t >> 6, l = t & 63;
    const int wm = w >> 1, wn = w & 1;
    const int quad = l >> 4, c15 = l & 15;

    const int lr  = l >> 3, ls = l & 7;  // DMA: row-in-8, slot

    floatx4 acc[MF][2] = {};

    for (int k0 = 0; k0 < K; k0 += 64) {
        // ---- stage A
        if constexpr (AMODE == A_DMA) {
            const unsigned short* Au = (const unsigned short*)Aptr + (long)bb * strideA;
            #pragma unroll
            for (int q = 0; q < TM / 32; ++q) {
                const int rt = q * 32 + w * 8;
                gload_lds16(Au + (long)(i0b + rt + lr) * lda + k0 + ((ls ^ lr) << 3),
                            &As[rt * 64]);
            }
        } else {  // A_F32ROW (NE over fp32 H), TM=64: 16 floats/thread
            const float* Af = (const float*)Aptr + (long)bb * strideA;
            const int ar  = t >> 2;
            const int ac0 = (t & 3) * 2;
            const float* ap = Af + (long)(i0b + ar) * lda + k0 + ac0 * 8;
            const float4 x0 = *(const float4*)(ap + 0);
            const float4 x1 = *(const float4*)(ap + 4);
            const float4 x2 = *(const float4*)(ap + 8);
            const float4 x3 = *(const float4*)(ap + 12);
            union { ush8 v; ushort2 u2[4]; } p0, p1;
            p0.u2[0] = pk2(x0.x, x0.y); p0.u2[1] = pk2(x0.z, x0.w);
            p0.u2[2] = pk2(x1.x, x1.y); p0.u2[3] = pk2(x1.z, x1.w);
            p1.u2[0] = pk2(x2.x, x2.y); p1.u2[1] = pk2(x2.z, x2.w);
            p1.u2[2] = pk2(x3.x, x3.y); p1.u2[3] = pk2(x3.z, x3.w);
            const int sw = ar & 7;
            *(ush8*)&As[ar * 64 + ((ac0 ^ sw) << 3)]       = p0.v;
            *(ush8*)&As[ar * 64 + (((ac0 + 1) ^ sw) << 3)] = p1.v;
        }
        // ---- stage B (always DMA)
        #pragma unroll
        for (int q = 0; q < 2; ++q) {
            const int rt = w * 16 + q * 8;
            gload_lds16(Btb + (long)(rt + lr) * K + k0 + ((ls ^ lr) << 3),
                        &Bs[rt * 64]);
        }
        __syncthreads();

        #pragma unroll
        for (int ks = 0; ks < 2; ++ks) {
            frag8 af[MF], bfv[2];
            const int swr = c15 & 7;
            #pragma unroll
            for (int mt = 0; mt < MF; ++mt)
                af[mt] = *(const frag8*)&As[(wm * (TM / 2) + mt * 16 + c15) * 64
                                            + (((ks * 4 + quad) ^ swr) << 3)];
            #pragma unroll
            for (int nt = 0; nt < 2; ++nt)
                bfv[nt] = *(const frag8*)&Bs[(wn * 32 + nt * 16 + c15) * 64
                                             + (((ks * 4 + quad) ^ swr) << 3)];
            #pragma unroll
            for (int mt = 0; mt < MF; ++mt)
                #pragma unroll
                for (int nt = 0; nt < 2; ++nt)
                    acc[mt][nt] = __builtin_amdgcn_mfma_f32_16x16x32_bf16(
                        af[mt], bfv[nt], acc[mt][nt], 0, 0, 0);
        }
        __syncthreads();
    }

    // ---- epilogue: C/D layout col=lane&15, row=quad*4+reg
    const long rowb = (long)bb * NN;
    #pragma unroll
    for (int mt = 0; mt < MF; ++mt) {
        const int il = wm * (TM / 2) + mt * 16 + quad * 4;
        const int ib = i0b + il;
        float4 s4 = make_float4(1.f, 1.f, 1.f, 1.f);
        if constexpr (EPI == EPI_M1) s4 = *(const float4*)(scale + rowb + ib);
        if constexpr (EPI == EPI_P2) {
            if (j0 < 256) s4 = *(const float4*)(scale + rowb + ib);
        }
        #pragma unroll
        for (int nt = 0; nt < 2; ++nt) {
            floatx4 v = acc[mt][nt];
            const int gj = j0 + wn * 32 + nt * 16 + c15;
            if constexpr (EPI == EPI_NE) {
                union { ushort4 v; ushort2 u2[2]; } p;
                p.u2[0] = pk2(v[0], v[1]); p.u2[1] = pk2(v[2], v[3]);
                *(ushort4*)(CsT + ((long)bb * 256 + gj) * 2048 + ib) = p.v;
            } else if constexpr (EPI == EPI_M1) {
                union { ushort4 v; ushort2 u2[2]; } p;
                p.u2[0] = pk2(v[0] * s4.x, v[1] * s4.y);
                p.u2[1] = pk2(v[2] * s4.z, v[3] * s4.w);
                *(ushort4*)(CsT + ((long)bb * 256 + gj) * 2048 + ib) = p.v;
            } else if constexpr (EPI == EPI_P2) {
                if (j0 < 256) {
                    union { ushort4 v; ushort2 u2[2]; } p;
                    p.u2[0] = pk2(v[0] * s4.x, v[1] * s4.y);
                    p.u2[1] = pk2(v[2] * s4.z, v[3] * s4.w);
                    *(ushort4*)(CsT + ((long)bb * 256 + gj) * 2048 + ib) = p.v;
                    // out1: reconstruct M1 = M1sT * rs_raw
                    const float4 rr = *(const float4*)(rsraw + rowb + ib);
                    const ushort4 m1p = *(const ushort4*)(B1 + ((long)bb * 256 + gj) * 2048 + ib);
                    const float m1v[4] = {bf2f(m1p.x) * rr.x, bf2f(m1p.y) * rr.y,
                                          bf2f(m1p.z) * rr.z, bf2f(m1p.w) * rr.w};
                    #pragma unroll
                    for (int r = 0; r < 4; ++r)
                        outp[(rowb + ib + r) * 768 + gj] = fmaxf(0.5f * (v[r] + m1v[r]), 0.f);
                } else {
                    #pragma unroll
                    for (int r = 0; r < 4; ++r)
                        outp[(rowb + ib + r) * 768 + gj] = fmaxf(v[r], 0.f);  // gj in [256,512)
                }
            } else {  // EPI_O3
                #pragma unroll
                for (int r = 0; r < 4; ++r)
                    outp[(rowb + ib + r) * 768 + 512 + gj] = fmaxf(v[r], 0.f);
            }
        }
    }
}

// ---- fused: G fp32 -> Gbf + GbfT + row/col partial sums ----
// R10: LDS-free rewrite. Old version was latency-bound at 2.5 TB/s
// (VGPR=52 proved the 16 loads were re-sunk into the cvt chain; phase B
// did 64 scalar ds_read_u16/thread). New structure: thread owns an 8x8
// block (wave = 64x64 sub-tile, 2x2 waves per 128x128 tile):
//   - all 16 float4 loads issued, sched_barrier(0) pins them ahead
//   - 8x8 bf16 transpose in registers (16-bit interleave, 2 bit-ops/dword)
//   - Gbf rows AND GbfT cols stored as ush8; per store instr the 64 lanes
//     cover 8 rows x 128 B contiguous (coalescer uses address set, not
//     lane order) -> full-line writes both directions
//   - row/col sums: 3-level shfl_xor trees, 32 partials per batch
//     (per j-half / i-half), no cross-wave LDS combine, no barrier
__global__ __launch_bounds__(256) void cvt_g(
    const float* __restrict__ G,
    unsigned short* __restrict__ Gbf, unsigned short* __restrict__ GbfT,
    float* __restrict__ prs, float* __restrict__ pcs)
{
    const int b  = blockIdx.z;
    const int j0 = blockIdx.x * 128, i0 = blockIdx.y * 128;
    const int t  = threadIdx.x;
    const int w  = t >> 6, l = t & 63;
    const int wm = w >> 1, wn = w & 1;     // i-half, j-half of the 128x128 tile
    const int rg = l >> 3, c = l & 7;      // i-block, j-block within 64x64

    const int ib = i0 + wm * 64 + rg * 8;  // global row base (8 rows)
    const int jb = j0 + wn * 64 + c * 8;   // global col base (8 cols)

    const float* gp = G + (long)b * GSTR + (long)ib * NN + jb;

    // ---- issue all 16 loads; forbid sinking them into the compute
    float4 xs[16];
    #pragma unroll
    for (int r = 0; r < 8; ++r) {
        xs[2 * r]     = *(const float4*)(gp + (long)r * NN);
        xs[2 * r + 1] = *(const float4*)(gp + (long)r * NN + 4);
    }
    __builtin_amdgcn_sched_barrier(0);

    union RowU { ush8 v; ushort2 u2[4]; unsigned u4[4]; };
    RowU rows[8];
    float csum[8] = {};
    float rsum[8];

    #pragma unroll
    for (int r = 0; r < 8; ++r) {
        const float4 x0 = xs[2 * r], x1 = xs[2 * r + 1];
        RowU rw;
        rw.u2[0] = pk2(x0.x, x0.y); rw.u2[1] = pk2(x0.z, x0.w);
        rw.u2[2] = pk2(x1.x, x1.y); rw.u2[3] = pk2(x1.z, x1.w);
        rows[r] = rw;
        *(ush8*)(Gbf + (long)b * GSTR + (long)(ib + r) * NN + jb) = rw.v;
        rsum[r] = x0.x + x0.y + x0.z + x0.w + x1.x + x1.y + x1.z + x1.w;
        csum[0] += x0.x; csum[1] += x0.y; csum[2] += x0.z; csum[3] += x0.w;
        csum[4] += x1.x; csum[5] += x1.y; csum[6] += x1.z; csum[7] += x1.w;
    }

    // ---- row sums: reduce across c (lane bits 0..2) -> 64-col partial
    #pragma unroll
    for (int r = 0; r < 8; ++r) {
        rsum[r] += __shfl_xor(rsum[r], 1);
        rsum[r] += __shfl_xor(rsum[r], 2);
        rsum[r] += __shfl_xor(rsum[r], 4);
    }
    if (c == 0) {
        float* pp = prs + ((long)b * 32 + blockIdx.x * 2 + wn) * NN + ib;
        *(float4*)pp       = make_float4(rsum[0], rsum[1], rsum[2], rsum[3]);
        *(float4*)(pp + 4) = make_float4(rsum[4], rsum[5], rsum[6], rsum[7]);
    }

    // ---- col sums: reduce across rg (lane bits 3..5) -> 64-row partial
    #pragma unroll
    for (int e = 0; e < 8; ++e) {
        csum[e] += __shfl_xor(csum[e], 8);
        csum[e] += __shfl_xor(csum[e], 16);
        csum[e] += __shfl_xor(csum[e], 32);
    }
    if (rg == 0) {
        float* pp = pcs + ((long)b * 32 + blockIdx.y * 2 + wm) * NN + jb;
        *(float4*)pp       = make_float4(csum[0], csum[1], csum[2], csum[3]);
        *(float4*)(pp + 4) = make_float4(csum[4], csum[5], csum[6], csum[7]);
    }

    // ---- 8x8 bf16 transpose in registers: 16-bit interleave of row pairs.
    // cols[j].u4[p] = {rows[2p] elem j (lo), rows[2p+1] elem j (hi)}
    RowU cols[8];
    #pragma unroll
    for (int p = 0; p < 4; ++p) {
        #pragma unroll
        for (int k = 0; k < 4; ++k) {
            const unsigned a = rows[2 * p].u4[k], bq = rows[2 * p + 1].u4[k];
            cols[2 * k].u4[p]     = (a & 0xffffu) | (bq << 16);
            cols[2 * k + 1].u4[p] = (a >> 16) | (bq & 0xffff0000u);
        }
    }
    #pragma unroll
    for (int j = 0; j < 8; ++j)
        *(ush8*)(GbfT + (long)b * GSTR + (long)(jb + j) * NN + ib) = cols[j].v;
}

// reduce partials + W transpose: y=0 -> inv_rs+rs_raw ; y=1 -> inv_cs ; y=2 -> Wt
__global__ __launch_bounds__(256) void finalize(
    const float* __restrict__ prs, const float* __restrict__ pcs,
    float* __restrict__ inv_rs, float* __restrict__ rs_raw,
    float* __restrict__ inv_cs,
    const float* __restrict__ W, unsigned short* __restrict__ Wt)
{
    const int idx = blockIdx.x * 256 + threadIdx.x;   // 0..16383
    if (blockIdx.y == 0) {
        const int b = idx >> 11, i = idx & 2047;
        float s = 0.f;
        #pragma unroll
        for (int jc = 0; jc < 32; ++jc) s += prs[((long)b * 32 + jc) * NN + i];
        inv_rs[idx] = 1.0f / s;
        rs_raw[idx] = s;
    } else if (blockIdx.y == 1) {
        const int b = idx >> 11, i = idx & 2047;
        float s = 0.f;
        #pragma unroll
        for (int ic = 0; ic < 32; ++ic) s += pcs[((long)b * 32 + ic) * NN + i];
        inv_cs[idx] = 1.0f / s;
    } else {
        #pragma unroll
        for (int e = 0; e < 4; ++e) {
            const int flat = idx * 4 + e;              // 0..65535
            const int j = flat >> 8, k = flat & 255;
            Wt[flat] = f2bf(W[(long)k * 256 + j]);
        }
    }
}

extern "C" void kernel_launch(void* const* d_in, const int* in_sizes, int n_in,
                              void* d_out, int out_size, void* d_ws, size_t ws_size,
                              hipStream_t stream)
{
    constexpr int B = 8;
    const float* H = (const float*)d_in[0];
    const float* G = (const float*)d_in[1];
    const float* W = (const float*)d_in[2];
    float* out = (float*)d_out;

    unsigned short* ws16 = (unsigned short*)d_ws;
    unsigned short* Gbf  = ws16;                          // 33,554,432 shorts
    unsigned short* GbfT = Gbf  + (long)B * GSTR;         // 33,554,432
    unsigned short* Wt   = GbfT + (long)B * GSTR;         // 65,536
    unsigned short* NeT  = Wt   + 65536;                  // 4,194,304
    unsigned short* M1sT = NeT  + 4194304;                // 4,194,304
    unsigned short* M2sT = M1sT + 4194304;                // 4,194,304
    float* inv_rs = (float*)(M2sT + 4194304);             // 16384
    float* rs_raw = inv_rs + 16384;
    float* inv_cs = rs_raw + 16384;
    float* prs    = inv_cs + 16384;                       // 8*32*2048
    float* pcs    = prs + (long)B * 32 * NN;              // 8*32*2048
    // total ~166 MB (ws = 512 MiB per harness fill WRITE_SIZE)

    cvt_g<<<dim3(16, 16, 8), 256, 0, stream>>>(G, Gbf, GbfT, prs, pcs);
    finalize<<<dim3(64, 3), 256, 0, stream>>>(prs, pcs, inv_rs, rs_raw, inv_cs, W, Wt);

    const long sNT = 256L * NN;
    // NeT = (H@W)^T : A=H fp32 [b][2048][256]  (TM=64, 32 i-tiles x 4 j x 8 b)
    mgemm<EPI_NE, A_F32ROW, 64, 4><<<1024, 256, 0, stream>>>(
        H, Wt, nullptr, nullptr, NeT, nullptr, nullptr,
        256, 256, 2048L * 256, 0);
    // M1sT = (G@Ne * inv_rs)^T   (TM=128: 16 i-tiles x 4 j x 8 b)
    mgemm<EPI_M1, A_DMA, 128, 4><<<512, 256, 0, stream>>>(
        Gbf, NeT, nullptr, nullptr, M1sT, nullptr, inv_rs,
        2048, 2048, GSTR, sNT);
    // P2: A=GbfT, B=[NeT ; M1sT] -> M2sT(scaled inv_cs) + out1 + out2 (8 j-tiles)
    mgemm<EPI_P2, A_DMA, 128, 8><<<1024, 256, 0, stream>>>(
        GbfT, NeT, M1sT, rs_raw, M2sT, out, inv_cs,
        2048, 2048, GSTR, sNT);
    // out3 = relu(G @ M2s)
    mgemm<EPI_O3, A_DMA, 128, 4><<<512, 256, 0, stream>>>(
        Gbf, M2sT, nullptr, nullptr, nullptr, out, nullptr,
        2048, 2048, GSTR, sNT);
}